// Round 2
// baseline (490.076 us; speedup 1.0000x reference)
//
#include <hip/hip_runtime.h>
#include <hip/hip_bf16.h>

#define EPSF 1e-5f

typedef __bf16 bf16x8 __attribute__((ext_vector_type(8)));
typedef float  f32x4  __attribute__((ext_vector_type(4)));
#define MFMA16(a, b, c) __builtin_amdgcn_mfma_f32_16x16x32_bf16((a), (b), (c), 0, 0, 0)

__device__ __forceinline__ bf16x8 ld_bf8(const __bf16* p) { return *(const bf16x8*)p; }

__device__ __forceinline__ unsigned short f2bf(float x) {
    unsigned int u = __float_as_uint(x);
    unsigned int r = (u + 0x7fffu + ((u >> 16) & 1u)) >> 16;
    return (unsigned short)r;
}

// ============================================================================
// setup1: role-multiplexed — gn_partial | styleproj | 4x wtrans | pos (16/blk)
// grid = 1024 + 48 + 64 + 64 + 128 + 128 + 256 = 1712
// ============================================================================
__device__ void wtrans_body(const float* __restrict__ W, unsigned short* __restrict__ Wt,
                            int K, int N, int L, int t, float* tile /*32x33*/) {
    int ktiles = K >> 5;
    int kt = L % ktiles, ntl = L / ktiles;
    int k0 = kt * 32, n0 = ntl * 32;
    int tc = t & 31, tr = t >> 5;
#pragma unroll
    for (int j = 0; j < 4; j++)
        tile[(tr + j * 8) * 33 + tc] = W[(size_t)(k0 + tr + j * 8) * N + n0 + tc];
    __syncthreads();
#pragma unroll
    for (int j = 0; j < 4; j++) {
        int r = tr + j * 8;
        Wt[(size_t)(n0 + r) * K + k0 + tc] = f2bf(tile[tc * 33 + r]);
    }
}

__global__ __launch_bounds__(256) void setup1_kernel(
    const float* __restrict__ x, float* __restrict__ part,
    const float* __restrict__ style, const float* __restrict__ Wg,
    const float* __restrict__ bg, const float* __restrict__ Ws,
    const float* __restrict__ bs, float* __restrict__ gp, float* __restrict__ tmp_s,
    const float* __restrict__ Wp1, const float* __restrict__ bp1,
    const float* __restrict__ Wp2, const float* __restrict__ bp2,
    float* __restrict__ pos,
    const float* __restrict__ Wq, const float* __restrict__ Wo,
    const float* __restrict__ Wf1, const float* __restrict__ Wf2,
    unsigned short* __restrict__ wq_t, unsigned short* __restrict__ wo_t,
    unsigned short* __restrict__ wf1_t, unsigned short* __restrict__ wf2_t)
{
    __shared__ float sm[4096];   // 16 KB, carved per role
    const int L = blockIdx.x, t = threadIdx.x;

    if (L < 1024) {
        // ---- GroupNorm partial stats: (b,g) = L>>4, sub = L&15 --------------
        int bg_ = L >> 4, sub = L & 15;
        const float4* p = (const float4*)(x + bg_ * 262144 + sub * 16384);
        float s = 0.f, q = 0.f;
#pragma unroll
        for (int i = 0; i < 16; i++) {
            float4 v = p[i * 256 + t];
            s += v.x + v.y + v.z + v.w;
            q += v.x * v.x + v.y * v.y + v.z * v.z + v.w * v.w;
        }
#pragma unroll
        for (int off = 32; off; off >>= 1) { s += __shfl_down(s, off); q += __shfl_down(q, off); }
        int lane = t & 63, w = t >> 6;
        if (lane == 0) { sm[w * 2] = s; sm[w * 2 + 1] = q; }
        __syncthreads();
        if (t == 0) {
            part[L * 2]     = sm[0] + sm[2] + sm[4] + sm[6];
            part[L * 2 + 1] = sm[1] + sm[3] + sm[5] + sm[7];
        }
    } else if (L < 1072) {
        // ---- style proj (unroll 8: 8 weight loads in flight) ----------------
        int lb = L - 1024, b = lb / 3, role = lb % 3;
        float* st = sm;
        st[t] = style[b * 512 + t];
        st[256 + t] = style[b * 512 + 256 + t];
        __syncthreads();
        if (role < 2) {
            int c = role * 256 + t;
            float acc = 0.f;
#pragma unroll 8
            for (int i = 0; i < 512; i++) acc += st[i] * Wg[i * 512 + c];
            gp[b * 512 + c] = acc + bg[c];
        } else {
            float acc = 0.f;
#pragma unroll 8
            for (int i = 0; i < 512; i++) acc += st[i] * Ws[i * 256 + t];
            tmp_s[b * 256 + t] = acc + bs[t];
        }
    } else if (L < 1136) {
        wtrans_body(Wq, wq_t, 256, 256, L - 1072, t, sm);
    } else if (L < 1200) {
        wtrans_body(Wo, wo_t, 256, 256, L - 1136, t, sm);
    } else if (L < 1328) {
        wtrans_body(Wf1, wf1_t, 256, 512, L - 1200, t, sm);
    } else if (L < 1456) {
        wtrans_body(Wf2, wf2_t, 512, 256, L - 1328, t, sm);
    } else {
        // ---- pos: 16 positions per block ------------------------------------
        int r = L - 1456, s0 = r * 16;
        float* pe = sm;    // 16 x 256
#pragma unroll
        for (int i = 0; i < 16; i++) {
            int sx = s0 + i;
            float gx = -1.f + 2.f * (float)(sx & 63) * (1.f / 63.f);
            float gy = -1.f + 2.f * (float)(sx >> 6) * (1.f / 63.f);
            float h = gx * Wp1[t] + gy * Wp1[256 + t] + bp1[t];
            pe[i * 256 + t] = h / (1.f + __expf(-h));
        }
        __syncthreads();
        float acc[16];
#pragma unroll
        for (int i = 0; i < 16; i++) acc[i] = 0.f;
#pragma unroll 8
        for (int k = 0; k < 256; k++) {
            float wv = Wp2[k * 256 + t];
#pragma unroll
            for (int i = 0; i < 16; i++) acc[i] += pe[i * 256 + k] * wv;
        }
        float bp = bp2[t];
#pragma unroll
        for (int i = 0; i < 16; i++) pos[(size_t)(s0 + i) * 256 + t] = acc[i] + bp;
    }
}

// ============================================================================
// kv2: fused token-LN + K/V projection (4 tokens/block) + gn_final (block 256)
// ============================================================================
__global__ __launch_bounds__(256) void kv2_kernel(
    const float* __restrict__ part, float* __restrict__ stats,
    const float* __restrict__ tokens, const float* __restrict__ tmp_s,
    const float* __restrict__ g, const float* __restrict__ bta,
    const float* __restrict__ Wk, const float* __restrict__ bk,
    const float* __restrict__ Wv, const float* __restrict__ bv,
    unsigned short* __restrict__ kb16, unsigned short* __restrict__ vt16)
{
    __shared__ float tr[4 * 256];
    __shared__ float red[32];
    const int blk = blockIdx.x, t = threadIdx.x;
    if (blk == 256) {
        if (t < 64) {
            float s = 0.f, q = 0.f;
            for (int i = 0; i < 16; i++) { s += part[(t * 16 + i) * 2]; q += part[(t * 16 + i) * 2 + 1]; }
            float m   = s * (1.f / 262144.f);
            float var = q * (1.f / 262144.f) - m * m;
            stats[t]      = m;
            stats[64 + t] = rsqrtf(var + EPSF);
        }
        return;
    }
    const int b = blk >> 4, tk0 = (blk & 15) * 4;
    const int lane = t & 63, w = t >> 6;
    const float tsv = tmp_s[b * 256 + t], gv = g[t], btv = bta[t];
#pragma unroll
    for (int j = 0; j < 4; j++) {
        float val = tokens[(tk0 + j) * 256 + t] + tsv;
        tr[j * 256 + t] = val;
        float s = val, q = val * val;
#pragma unroll
        for (int off = 32; off; off >>= 1) { s += __shfl_down(s, off); q += __shfl_down(q, off); }
        if (lane == 0) { red[j * 8 + w * 2] = s; red[j * 8 + w * 2 + 1] = q; }
    }
    __syncthreads();
#pragma unroll
    for (int j = 0; j < 4; j++) {
        float s = red[j * 8] + red[j * 8 + 2] + red[j * 8 + 4] + red[j * 8 + 6];
        float q = red[j * 8 + 1] + red[j * 8 + 3] + red[j * 8 + 5] + red[j * 8 + 7];
        float m = s * (1.f / 256.f);
        float var = q * (1.f / 256.f) - m * m;
        float r = rsqrtf(var + EPSF);
        tr[j * 256 + t] = (tr[j * 256 + t] - m) * r * gv + btv;
    }
    __syncthreads();
    float ak[4] = {0.f, 0.f, 0.f, 0.f}, av[4] = {0.f, 0.f, 0.f, 0.f};
#pragma unroll 4
    for (int i = 0; i < 256; i++) {
        float wk = Wk[i * 256 + t], wv = Wv[i * 256 + t];
#pragma unroll
        for (int j = 0; j < 4; j++) { ak[j] += tr[j * 256 + i] * wk; av[j] += tr[j * 256 + i] * wv; }
    }
    float bkv = bk[t], bvv = bv[t];
#pragma unroll
    for (int j = 0; j < 4; j++)
        kb16[((size_t)(b * 64 + tk0 + j)) * 256 + t] = f2bf(ak[j] + bkv);
    ushort4 vp;
    vp.x = f2bf(av[0] + bvv); vp.y = f2bf(av[1] + bvv);
    vp.z = f2bf(av[2] + bvv); vp.w = f2bf(av[3] + bvv);
    *(ushort4*)&vt16[((size_t)(b * 256 + t)) * 64 + tk0] = vp;
}

// ============================================================================
// Mega kernel v3. Block = (b, 32-row s-tile). LDS = 35,328 B -> 4 blocks/CU.
// All weight streams software-pipelined (double-buffered B-fragments).
// S2 writes q to Qb (PsB overlay) so A streams lazily from LDS (no af pin).
// S3 prefetches K before barrier, V before softmax.
// ============================================================================
__global__ __launch_bounds__(256, 4) void mega_kernel(
    const float* __restrict__ x, const float* __restrict__ stats,
    const float* __restrict__ pos,
    const __bf16* __restrict__ kb, const __bf16* __restrict__ vt,
    const float* __restrict__ gp,
    const float* __restrict__ lnq_g, const float* __restrict__ lnq_b,
    const float* __restrict__ lnf_g, const float* __restrict__ lnf_b,
    const __bf16* __restrict__ Wq_t, const float* __restrict__ bq,
    const __bf16* __restrict__ Wo_t, const float* __restrict__ bo,
    const __bf16* __restrict__ Wf1_t, const float* __restrict__ bf1,
    const __bf16* __restrict__ Wf2_t, const float* __restrict__ bf2,
    const float* __restrict__ gamma, float* __restrict__ out)
{
    __shared__ __align__(16) unsigned char smraw[35328];
    __bf16* Ab  = (__bf16*)smraw;                 // 32 x 264 bf16 = 16,896 B
    __bf16* PsB = (__bf16*)(smraw + 16896);       // 18,432 B scratch region
    __bf16* Qb  = PsB;                            // overlay: q 32 x 264 = 16,896 B
    __bf16* H   = (__bf16*)smraw;                 // overlay: 32 x 536 bf16 = 34,304 B
    float*  T   = (float*)smraw;                  // overlay: 32 x 268 f32  = 34,304 B
    float* psum   = (float*)(smraw + 16896);      // stats overlays (PsB region)
    float* psq    = psum + 256;
    float* rowred = psum + 512;

    const int blk  = blockIdx.x;        // 2048 = 16 b * 128 tiles
    const int b    = blk >> 7;
    const int s0   = (blk & 127) * 32;
    const int t    = threadIdx.x;
    const int w    = t >> 6;
    const int lane = t & 63;
    const int quad = lane >> 4;
    const int l16  = lane & 15;

    const float mg = stats[b * 4 + (t >> 6)];
    const float rg = stats[64 + b * 4 + (t >> 6)];
    const f32x4 z4 = {0.f, 0.f, 0.f, 0.f};

    // ---- S1: Ab = bf16(GN(x)+pos); row stats; LN_q in place ------------------
    {
        const float4* xp = (const float4*)(x + (size_t)(b * 256 + t) * 4096 + s0);
        float xv[32];
#pragma unroll
        for (int i = 0; i < 8; i++) {
            float4 v = xp[i];
            xv[4*i] = v.x; xv[4*i+1] = v.y; xv[4*i+2] = v.z; xv[4*i+3] = v.w;
        }
#pragma unroll
        for (int i = 0; i < 32; i++)
            Ab[i * 264 + t] = (__bf16)((xv[i] - mg) * rg + pos[(size_t)(s0 + i) * 256 + t]);
    }
    __syncthreads();
    {
        int sl = t & 31, cg = t >> 5;
        float s = 0.f, q = 0.f;
#pragma unroll
        for (int j = 0; j < 4; j++) {
            bf16x8 v8 = ld_bf8(&Ab[sl * 264 + cg * 32 + j * 8]);
#pragma unroll
            for (int e = 0; e < 8; e++) { float f = (float)v8[e]; s += f; q += f * f; }
        }
        psum[cg * 32 + sl] = s; psq[cg * 32 + sl] = q;
    }
    __syncthreads();
    if (t < 32) {
        float S = 0.f, Q = 0.f;
        for (int p = 0; p < 8; p++) { S += psum[p * 32 + t]; Q += psq[p * 32 + t]; }
        float m = S * (1.f / 256.f);
        float var = Q * (1.f / 256.f) - m * m;
        rowred[t * 2] = m; rowred[t * 2 + 1] = rsqrtf(var + EPSF);
    }
    __syncthreads();
    {
        float gq = lnq_g[t], bqv = lnq_b[t];
#pragma unroll
        for (int i = 0; i < 32; i++) {
            float v = (float)Ab[i * 264 + t];
            Ab[i * 264 + t] = (__bf16)((v - rowred[i * 2]) * rowred[i * 2 + 1] * gq + bqv);
        }
    }
    __syncthreads();

    // ---- S2: q = Ab @ Wq + bq -> Qb (lazy A from LDS, wb double-buffer) ------
    {
        bf16x8 wb[2][8];
#pragma unroll
        for (int ks = 0; ks < 8; ks++)
            wb[0][ks] = ld_bf8(&Wq_t[(size_t)(w * 64 + l16) * 256 + ks * 32 + quad * 8]);
#pragma unroll
        for (int nt = 0; nt < 4; nt++) {
            const int cur = nt & 1;
            if (nt < 3) {
                int nn = w * 64 + (nt + 1) * 16 + l16;
#pragma unroll
                for (int ks = 0; ks < 8; ks++)
                    wb[cur ^ 1][ks] = ld_bf8(&Wq_t[(size_t)nn * 256 + ks * 32 + quad * 8]);
            }
            int n = w * 64 + nt * 16 + l16;
            f32x4 a0 = z4, a1 = z4;
#pragma unroll
            for (int ks = 0; ks < 8; ks++) {
                a0 = MFMA16(ld_bf8(&Ab[l16 * 264 + ks * 32 + quad * 8]), wb[cur][ks], a0);
                a1 = MFMA16(ld_bf8(&Ab[(16 + l16) * 264 + ks * 32 + quad * 8]), wb[cur][ks], a1);
            }
            float bias = bq[n];
#pragma unroll
            for (int r = 0; r < 4; r++) {
                Qb[(quad * 4 + r) * 264 + n]      = (__bf16)(a0[r] + bias);
                Qb[(16 + quad * 4 + r) * 264 + n] = (__bf16)(a1[r] + bias);
            }
        }
    }

    // ---- S3: attention, head = w, 32 rows ------------------------------------
    {
        const int h = w;
        __bf16* Psw = PsB + w * 32 * 72;
        bf16x8 qa[2][2];
#pragma unroll
        for (int rt = 0; rt < 2; rt++)
#pragma unroll
            for (int k0 = 0; k0 < 2; k0++)
                qa[rt][k0] = ld_bf8(&Qb[(rt * 16 + l16) * 264 + h * 64 + k0 * 32 + quad * 8]);
        // prefetch K fragments (hide global latency behind the barrier)
        bf16x8 kf[4][2];
#pragma unroll
        for (int nt = 0; nt < 4; nt++)
#pragma unroll
            for (int k0 = 0; k0 < 2; k0++)
                kf[nt][k0] = ld_bf8(&kb[((size_t)(b * 64 + nt * 16 + l16)) * 256 + h * 64 + k0 * 32 + quad * 8]);
        // barrier: all S2 Ab-reads and all Qb-reads complete -> P/O writes safe
        __syncthreads();
        f32x4 sa[2][4];
#pragma unroll
        for (int rt = 0; rt < 2; rt++)
#pragma unroll
            for (int nt = 0; nt < 4; nt++) sa[rt][nt] = z4;
#pragma unroll
        for (int nt = 0; nt < 4; nt++)
#pragma unroll
            for (int k0 = 0; k0 < 2; k0++) {
                sa[0][nt] = MFMA16(qa[0][k0], kf[nt][k0], sa[0][nt]);
                sa[1][nt] = MFMA16(qa[1][k0], kf[nt][k0], sa[1][nt]);
            }
        // prefetch V fragments: latency hides under softmax VALU chain
        bf16x8 vf[4][2];
#pragma unroll
        for (int nt = 0; nt < 4; nt++)
#pragma unroll
            for (int k0 = 0; k0 < 2; k0++)
                vf[nt][k0] = ld_bf8(&vt[((size_t)(b * 256 + h * 64 + nt * 16 + l16)) * 64 + k0 * 32 + quad * 8]);
        // softmax per row; P -> Psw (bf16)
#pragma unroll
        for (int rt = 0; rt < 2; rt++)
#pragma unroll
            for (int r = 0; r < 4; r++) {
                float e0 = sa[rt][0][r] * 0.25f, e1 = sa[rt][1][r] * 0.25f;
                float e2 = sa[rt][2][r] * 0.25f, e3 = sa[rt][3][r] * 0.25f;
                float mx = fmaxf(fmaxf(e0, e1), fmaxf(e2, e3));
#pragma unroll
                for (int off = 1; off < 16; off <<= 1) mx = fmaxf(mx, __shfl_xor(mx, off));
                e0 = __expf(e0 - mx); e1 = __expf(e1 - mx);
                e2 = __expf(e2 - mx); e3 = __expf(e3 - mx);
                float sum = e0 + e1 + e2 + e3;
#pragma unroll
                for (int off = 1; off < 16; off <<= 1) sum += __shfl_xor(sum, off);
                float inv = 1.f / sum;
                int row = rt * 16 + quad * 4 + r;
                Psw[row * 72 +  0 + l16] = (__bf16)(e0 * inv);
                Psw[row * 72 + 16 + l16] = (__bf16)(e1 * inv);
                Psw[row * 72 + 32 + l16] = (__bf16)(e2 * inv);
                Psw[row * 72 + 48 + l16] = (__bf16)(e3 * inv);
            }
        // O = P @ V_h -> Ab cols [h*64, h*64+64)  (same-wave LDS, in order)
        bf16x8 pa[2][2];
#pragma unroll
        for (int rt = 0; rt < 2; rt++)
#pragma unroll
            for (int k0 = 0; k0 < 2; k0++)
                pa[rt][k0] = ld_bf8(&Psw[(rt * 16 + l16) * 72 + k0 * 32 + quad * 8]);
#pragma unroll
        for (int nt = 0; nt < 4; nt++) {
            f32x4 o0 = z4, o1 = z4;
#pragma unroll
            for (int k0 = 0; k0 < 2; k0++) {
                o0 = MFMA16(pa[0][k0], vf[nt][k0], o0);
                o1 = MFMA16(pa[1][k0], vf[nt][k0], o1);
            }
#pragma unroll
            for (int r = 0; r < 4; r++) {
                Ab[(quad * 4 + r) * 264 + h * 64 + nt * 16 + l16]      = (__bf16)o0[r];
                Ab[(16 + quad * 4 + r) * 264 + h * 64 + nt * 16 + l16] = (__bf16)o1[r];
            }
        }
    }
    __syncthreads();

    // ---- S4: sc = Ab @ Wo + bo -> f32 regs (lazy A, wb double-buffer) --------
    f32x4 scf[2][4];
    {
        bf16x8 wb[2][8];
#pragma unroll
        for (int ks = 0; ks < 8; ks++)
            wb[0][ks] = ld_bf8(&Wo_t[(size_t)(w * 64 + l16) * 256 + ks * 32 + quad * 8]);
#pragma unroll
        for (int nt = 0; nt < 4; nt++) {
            const int cur = nt & 1;
            if (nt < 3) {
                int nn = w * 64 + (nt + 1) * 16 + l16;
#pragma unroll
                for (int ks = 0; ks < 8; ks++)
                    wb[cur ^ 1][ks] = ld_bf8(&Wo_t[(size_t)nn * 256 + ks * 32 + quad * 8]);
            }
            int n = w * 64 + nt * 16 + l16;
            f32x4 a0 = z4, a1 = z4;
#pragma unroll
            for (int ks = 0; ks < 8; ks++) {
                a0 = MFMA16(ld_bf8(&Ab[l16 * 264 + ks * 32 + quad * 8]), wb[cur][ks], a0);
                a1 = MFMA16(ld_bf8(&Ab[(16 + l16) * 264 + ks * 32 + quad * 8]), wb[cur][ks], a1);
            }
            float bias = bo[n];
#pragma unroll
            for (int r = 0; r < 4; r++) { a0[r] += bias; a1[r] += bias; }
            scf[0][nt] = a0;
            scf[1][nt] = a1;
        }
    }

    // ---- S5: row stats of sc from registers ----------------------------------
    {
#pragma unroll
        for (int rt = 0; rt < 2; rt++)
#pragma unroll
            for (int r = 0; r < 4; r++) {
                float s = scf[rt][0][r] + scf[rt][1][r] + scf[rt][2][r] + scf[rt][3][r];
                float q = scf[rt][0][r] * scf[rt][0][r] + scf[rt][1][r] * scf[rt][1][r]
                        + scf[rt][2][r] * scf[rt][2][r] + scf[rt][3][r] * scf[rt][3][r];
#pragma unroll
                for (int mk = 1; mk < 16; mk <<= 1) { s += __shfl_xor(s, mk); q += __shfl_xor(q, mk); }
                if (l16 == 0) {
                    int row = rt * 16 + quad * 4 + r;
                    psum[row * 4 + w] = s;
                    psq[row * 4 + w]  = q;
                }
            }
    }
    __syncthreads();
    if (t < 32) {
        float S = psum[t * 4] + psum[t * 4 + 1] + psum[t * 4 + 2] + psum[t * 4 + 3];
        float Q = psq[t * 4]  + psq[t * 4 + 1]  + psq[t * 4 + 2]  + psq[t * 4 + 3];
        float m = S * (1.f / 256.f);
        float var = Q * (1.f / 256.f) - m * m;
        rowred[t * 2] = m; rowred[t * 2 + 1] = rsqrtf(var + EPSF);
    }
    __syncthreads();

    // ---- LN_f from registers -> Ab (bf16, MFMA-A layout) ---------------------
    {
        float gf[4], bff[4];
#pragma unroll
        for (int nt = 0; nt < 4; nt++) {
            int n = w * 64 + nt * 16 + l16;
            gf[nt] = lnf_g[n]; bff[nt] = lnf_b[n];
        }
#pragma unroll
        for (int rt = 0; rt < 2; rt++)
#pragma unroll
            for (int r = 0; r < 4; r++) {
                int row = rt * 16 + quad * 4 + r;
                float m = rowred[row * 2], ri = rowred[row * 2 + 1];
#pragma unroll
                for (int nt = 0; nt < 4; nt++) {
                    int n = w * 64 + nt * 16 + l16;
                    Ab[row * 264 + n] = (__bf16)((scf[rt][nt][r] - m) * ri * gf[nt] + bff[nt]);
                }
            }
    }
    __syncthreads();

    // ---- FFN: FF1 (fa preload, 4-deep wb ping-pong) -> H; FF2 (wb dbuf) ------
    f32x4 acc2[2][4];
#pragma unroll
    for (int rt = 0; rt < 2; rt++)
#pragma unroll
        for (int nt = 0; nt < 4; nt++) acc2[rt][nt] = z4;
    {
        bf16x8 fa[2][8];
#pragma unroll
        for (int rt = 0; rt < 2; rt++)
#pragma unroll
            for (int ks = 0; ks < 8; ks++)
                fa[rt][ks] = ld_bf8(&Ab[(rt * 16 + l16) * 264 + ks * 32 + quad * 8]);
        __syncthreads();   // all fa loaded; H overlay (covers Ab+PsB) now safe

        // FF1: wave w computes h1 cols [w*128, w*128+128); 16 half-groups of 4 ks
        {
            bf16x8 wp[4];
            {
                int n1 = w * 128 + l16;
#pragma unroll
                for (int kk = 0; kk < 4; kk++)
                    wp[kk] = ld_bf8(&Wf1_t[(size_t)n1 * 256 + kk * 32 + quad * 8]);
            }
            f32x4 h0 = z4, h1 = z4;
#pragma unroll
            for (int half = 0; half < 16; half++) {
                const int c = half >> 1, ph = half & 1;
                bf16x8 wn[4];
                if (half < 15) {
                    const int hn = half + 1;
                    const int n1n = w * 128 + (hn >> 1) * 16 + l16;
                    const int ksb = (hn & 1) * 4;
#pragma unroll
                    for (int kk = 0; kk < 4; kk++)
                        wn[kk] = ld_bf8(&Wf1_t[(size_t)n1n * 256 + (ksb + kk) * 32 + quad * 8]);
                }
#pragma unroll
                for (int kk = 0; kk < 4; kk++) {
                    const int ks = ph * 4 + kk;
                    h0 = MFMA16(fa[0][ks], wp[kk], h0);
                    h1 = MFMA16(fa[1][ks], wp[kk], h1);
                }
                if (ph == 1) {
                    const int n1 = w * 128 + c * 16 + l16;
                    float b1v = bf1[n1];
#pragma unroll
                    for (int r = 0; r < 4; r++) {
                        float u0 = h0[r] + b1v;
                        float u1 = h1[r] + b1v;
                        H[(quad * 4 + r) * 536 + n1]      = (__bf16)(u0 / (1.f + __expf(-u0)));
                        H[(16 + quad * 4 + r) * 536 + n1] = (__bf16)(u1 / (1.f + __expf(-u1)));
                    }
                    h0 = z4; h1 = z4;
                }
#pragma unroll
                for (int kk = 0; kk < 4; kk++) wp[kk] = wn[kk];
            }
        }
        __syncthreads();   // full H visible

        // FF2: K=512, wb[2][4] double-buffer across k0
        {
            bf16x8 wb[2][4];
#pragma unroll
            for (int nt = 0; nt < 4; nt++)
                wb[0][nt] = ld_bf8(&Wf2_t[(size_t)(w * 64 + nt * 16 + l16) * 512 + quad * 8]);
#pragma unroll
            for (int k0 = 0; k0 < 16; k0++) {
                const int cur = k0 & 1;
                if (k0 < 15) {
#pragma unroll
                    for (int nt = 0; nt < 4; nt++)
                        wb[cur ^ 1][nt] = ld_bf8(&Wf2_t[(size_t)(w * 64 + nt * 16 + l16) * 512 + (k0 + 1) * 32 + quad * 8]);
                }
                bf16x8 ha0 = ld_bf8(&H[(size_t)l16 * 536 + k0 * 32 + quad * 8]);
                bf16x8 ha1 = ld_bf8(&H[(size_t)(16 + l16) * 536 + k0 * 32 + quad * 8]);
#pragma unroll
                for (int nt = 0; nt < 4; nt++) {
                    acc2[0][nt] = MFMA16(ha0, wb[cur][nt], acc2[0][nt]);
                    acc2[1][nt] = MFMA16(ha1, wb[cur][nt], acc2[1][nt]);
                }
            }
        }
    }
    __syncthreads();   // all H reads done before T overlay writes

    // ---- sc_final = sc + ffn + bf2 -> T (f32 transpose buffer) ---------------
    {
#pragma unroll
        for (int nt = 0; nt < 4; nt++) {
            int n = w * 64 + nt * 16 + l16;
            float b2 = bf2[n];
#pragma unroll
            for (int rt = 0; rt < 2; rt++)
#pragma unroll
                for (int r = 0; r < 4; r++)
                    T[(rt * 16 + quad * 4 + r) * 268 + n] = scf[rt][nt][r] + acc2[rt][nt][r] + b2;
        }
    }
    __syncthreads();

    // ---- S6: out[b,c,s] = GN(x)*scale + shift + sc*gamma ---------------------
    {
        const float scl = gp[b * 512 + t];
        const float sft = gp[b * 512 + 256 + t];
        const float gm  = gamma[t];
        const float4* xp = (const float4*)(x + (size_t)(b * 256 + t) * 4096 + s0);
        float4* op = (float4*)(out + (size_t)(b * 256 + t) * 4096 + s0);
#pragma unroll
        for (int ii = 0; ii < 8; ii++) {
            float4 xv = xp[ii];
            float4 o;
            o.x = (xv.x - mg) * rg * scl + sft + T[(ii * 4 + 0) * 268 + t] * gm;
            o.y = (xv.y - mg) * rg * scl + sft + T[(ii * 4 + 1) * 268 + t] * gm;
            o.z = (xv.z - mg) * rg * scl + sft + T[(ii * 4 + 2) * 268 + t] * gm;
            o.w = (xv.w - mg) * rg * scl + sft + T[(ii * 4 + 3) * 268 + t] * gm;
            op[ii] = o;
        }
    }
}

// ============================================================================
extern "C" void kernel_launch(void* const* d_in, const int* in_sizes, int n_in,
                              void* d_out, int out_size, void* d_ws, size_t ws_size,
                              hipStream_t stream) {
    (void)in_sizes; (void)n_in; (void)out_size; (void)ws_size;
    const float* x      = (const float*)d_in[0];
    const float* style  = (const float*)d_in[1];
    const float* Wg     = (const float*)d_in[2];
    const float* bg     = (const float*)d_in[3];
    const float* tokens = (const float*)d_in[4];
    const float* Ws     = (const float*)d_in[5];
    const float* bs     = (const float*)d_in[6];
    const float* Wp1    = (const float*)d_in[7];
    const float* bp1    = (const float*)d_in[8];
    const float* Wp2    = (const float*)d_in[9];
    const float* bp2    = (const float*)d_in[10];
    const float* ln_t_g = (const float*)d_in[11];
    const float* ln_t_b = (const float*)d_in[12];
    const float* ln_q_g = (const float*)d_in[13];
    const float* ln_q_b = (const float*)d_in[14];
    const float* ln_f_g = (const float*)d_in[15];
    const float* ln_f_b = (const float*)d_in[16];
    const float* Wq     = (const float*)d_in[17];
    const float* bq     = (const float*)d_in[18];
    const float* Wk     = (const float*)d_in[19];
    const float* bk     = (const float*)d_in[20];
    const float* Wv     = (const float*)d_in[21];
    const float* bv     = (const float*)d_in[22];
    const float* Wo     = (const float*)d_in[23];
    const float* bo     = (const float*)d_in[24];
    const float* Wf1    = (const float*)d_in[25];
    const float* bf1    = (const float*)d_in[26];
    const float* Wf2    = (const float*)d_in[27];
    const float* bf2    = (const float*)d_in[28];
    const float* gamma  = (const float*)d_in[29];
    float* out = (float*)d_out;

    // d_ws layout (~7.1 MB)
    float* ws = (float*)d_ws;
    float* part  = ws;               // 2048
    float* stats = part  + 2048;     // 128
    float* gpb   = stats + 128;      // 8192
    float* tmp_s = gpb   + 8192;     // 4096
    float* tokb  = tmp_s + 4096;     // 262144 (unused, kept for layout stability)
    float* posb  = tokb  + 262144;   // 1048576
    unsigned short* kb16  = (unsigned short*)(posb + 1048576); // 262144 bf16
    unsigned short* vt16  = kb16  + 262144;                    // 262144
    unsigned short* wq_t  = vt16  + 262144;                    // 65536
    unsigned short* wo_t  = wq_t  + 65536;                     // 65536
    unsigned short* wf1_t = wo_t  + 65536;                     // 131072
    unsigned short* wf2_t = wf1_t + 131072;                    // 131072

    setup1_kernel<<<1712, 256, 0, stream>>>(x, part, style, Wg, bg, Ws, bs, gpb, tmp_s,
                                            Wp1, bp1, Wp2, bp2, posb,
                                            Wq, Wo, Wf1, Wf2,
                                            wq_t, wo_t, wf1_t, wf2_t);
    kv2_kernel<<<257, 256, 0, stream>>>(part, stats, tokens, tmp_s, ln_t_g, ln_t_b,
                                        Wk, bk, Wv, bv, kb16, vt16);
    mega_kernel<<<2048, 256, 0, stream>>>(x, stats, posb,
                                          (const __bf16*)kb16, (const __bf16*)vt16, gpb,
                                          ln_q_g, ln_q_b, ln_f_g, ln_f_b,
                                          (const __bf16*)wq_t, bq,
                                          (const __bf16*)wo_t, bo,
                                          (const __bf16*)wf1_t, bf1,
                                          (const __bf16*)wf2_t, bf2,
                                          gamma, out);
}

// Round 3
// 405.455 us; speedup vs baseline: 1.2087x; 1.2087x over previous
//
#include <hip/hip_runtime.h>
#include <hip/hip_bf16.h>

#define EPSF 1e-5f

typedef __bf16 bf16x8 __attribute__((ext_vector_type(8)));
typedef float  f32x4  __attribute__((ext_vector_type(4)));
#define MFMA16(a, b, c) __builtin_amdgcn_mfma_f32_16x16x32_bf16((a), (b), (c), 0, 0, 0)

__device__ __forceinline__ bf16x8 ld_bf8(const __bf16* p) { return *(const bf16x8*)p; }

__device__ __forceinline__ unsigned short f2bf(float x) {
    unsigned int u = __float_as_uint(x);
    unsigned int r = (u + 0x7fffu + ((u >> 16) & 1u)) >> 16;
    return (unsigned short)r;
}

// Packed fragment layout: [n>>4][k>>5][(k>>3)&3][n&15][k&7]
// -> one wave MFMA B-fragment (16 lanes l16 x 4 quads x 8 elems) = 1024
//    CONTIGUOUS bytes. Fixes the 64-line L2 gather of the n*K+k layout.
__device__ __forceinline__ size_t pk_idx(int n, int k, int K) {
    return ((size_t)(((n >> 4) * (K >> 5) + (k >> 5)) * 4 + ((k >> 3) & 3)) * 16
            + (n & 15)) * 8 + (k & 7);
}

// ============================================================================
// setup1: role-multiplexed — gn_partial | styleproj | 4x wtrans | pos (16/blk)
// grid = 1024 + 48 + 64 + 64 + 128 + 128 + 256 = 1712
// ============================================================================
__device__ void wtrans_body(const float* __restrict__ W, unsigned short* __restrict__ Wt,
                            int K, int N, int L, int t, float* tile /*32x33*/) {
    int ktiles = K >> 5;
    int kt = L % ktiles, ntl = L / ktiles;
    int k0 = kt * 32, n0 = ntl * 32;
    int tc = t & 31, tr = t >> 5;
#pragma unroll
    for (int j = 0; j < 4; j++)
        tile[(tr + j * 8) * 33 + tc] = W[(size_t)(k0 + tr + j * 8) * N + n0 + tc];
    __syncthreads();
#pragma unroll
    for (int j = 0; j < 4; j++) {
        int r = tr + j * 8;
        Wt[pk_idx(n0 + r, k0 + tc, K)] = f2bf(tile[tc * 33 + r]);
    }
}

__global__ __launch_bounds__(256) void setup1_kernel(
    const float* __restrict__ x, float* __restrict__ part,
    const float* __restrict__ style, const float* __restrict__ Wg,
    const float* __restrict__ bg, const float* __restrict__ Ws,
    const float* __restrict__ bs, float* __restrict__ gp, float* __restrict__ tmp_s,
    const float* __restrict__ Wp1, const float* __restrict__ bp1,
    const float* __restrict__ Wp2, const float* __restrict__ bp2,
    float* __restrict__ pos,
    const float* __restrict__ Wq, const float* __restrict__ Wo,
    const float* __restrict__ Wf1, const float* __restrict__ Wf2,
    unsigned short* __restrict__ wq_t, unsigned short* __restrict__ wo_t,
    unsigned short* __restrict__ wf1_t, unsigned short* __restrict__ wf2_t)
{
    __shared__ float sm[4096];   // 16 KB, carved per role
    const int L = blockIdx.x, t = threadIdx.x;

    if (L < 1024) {
        // ---- GroupNorm partial stats: (b,g) = L>>4, sub = L&15 --------------
        int bg_ = L >> 4, sub = L & 15;
        const float4* p = (const float4*)(x + bg_ * 262144 + sub * 16384);
        float s = 0.f, q = 0.f;
#pragma unroll
        for (int i = 0; i < 16; i++) {
            float4 v = p[i * 256 + t];
            s += v.x + v.y + v.z + v.w;
            q += v.x * v.x + v.y * v.y + v.z * v.z + v.w * v.w;
        }
#pragma unroll
        for (int off = 32; off; off >>= 1) { s += __shfl_down(s, off); q += __shfl_down(q, off); }
        int lane = t & 63, w = t >> 6;
        if (lane == 0) { sm[w * 2] = s; sm[w * 2 + 1] = q; }
        __syncthreads();
        if (t == 0) {
            part[L * 2]     = sm[0] + sm[2] + sm[4] + sm[6];
            part[L * 2 + 1] = sm[1] + sm[3] + sm[5] + sm[7];
        }
    } else if (L < 1072) {
        // ---- style proj ------------------------------------------------------
        int lb = L - 1024, b = lb / 3, role = lb % 3;
        float* st = sm;
        st[t] = style[b * 512 + t];
        st[256 + t] = style[b * 512 + 256 + t];
        __syncthreads();
        if (role < 2) {
            int c = role * 256 + t;
            float acc = 0.f;
            for (int i = 0; i < 512; i++) acc += st[i] * Wg[i * 512 + c];
            gp[b * 512 + c] = acc + bg[c];
        } else {
            float acc = 0.f;
            for (int i = 0; i < 512; i++) acc += st[i] * Ws[i * 256 + t];
            tmp_s[b * 256 + t] = acc + bs[t];
        }
    } else if (L < 1136) {
        wtrans_body(Wq, wq_t, 256, 256, L - 1072, t, sm);
    } else if (L < 1200) {
        wtrans_body(Wo, wo_t, 256, 256, L - 1136, t, sm);
    } else if (L < 1328) {
        wtrans_body(Wf1, wf1_t, 256, 512, L - 1200, t, sm);
    } else if (L < 1456) {
        wtrans_body(Wf2, wf2_t, 512, 256, L - 1328, t, sm);
    } else {
        // ---- pos: 16 positions per block ------------------------------------
        int r = L - 1456, s0 = r * 16;
        float* pe = sm;    // 16 x 256
#pragma unroll
        for (int i = 0; i < 16; i++) {
            int sx = s0 + i;
            float gx = -1.f + 2.f * (float)(sx & 63) * (1.f / 63.f);
            float gy = -1.f + 2.f * (float)(sx >> 6) * (1.f / 63.f);
            float h = gx * Wp1[t] + gy * Wp1[256 + t] + bp1[t];
            pe[i * 256 + t] = h / (1.f + __expf(-h));
        }
        __syncthreads();
        float acc[16];
#pragma unroll
        for (int i = 0; i < 16; i++) acc[i] = 0.f;
#pragma unroll 4
        for (int k = 0; k < 256; k++) {
            float wv = Wp2[k * 256 + t];
#pragma unroll
            for (int i = 0; i < 16; i++) acc[i] += pe[i * 256 + k] * wv;
        }
        float bp = bp2[t];
#pragma unroll
        for (int i = 0; i < 16; i++) pos[(size_t)(s0 + i) * 256 + t] = acc[i] + bp;
    }
}

// ============================================================================
// kv2: fused token-LN + K/V projection (4 tokens/block) + gn_final (block 256)
// ============================================================================
__global__ __launch_bounds__(256) void kv2_kernel(
    const float* __restrict__ part, float* __restrict__ stats,
    const float* __restrict__ tokens, const float* __restrict__ tmp_s,
    const float* __restrict__ g, const float* __restrict__ bta,
    const float* __restrict__ Wk, const float* __restrict__ bk,
    const float* __restrict__ Wv, const float* __restrict__ bv,
    unsigned short* __restrict__ kb16, unsigned short* __restrict__ vt16)
{
    __shared__ float tr[4 * 256];
    __shared__ float red[32];
    const int blk = blockIdx.x, t = threadIdx.x;
    if (blk == 256) {
        if (t < 64) {
            float s = 0.f, q = 0.f;
            for (int i = 0; i < 16; i++) { s += part[(t * 16 + i) * 2]; q += part[(t * 16 + i) * 2 + 1]; }
            float m   = s * (1.f / 262144.f);
            float var = q * (1.f / 262144.f) - m * m;
            stats[t]      = m;
            stats[64 + t] = rsqrtf(var + EPSF);
        }
        return;
    }
    const int b = blk >> 4, tk0 = (blk & 15) * 4;
    const int lane = t & 63, w = t >> 6;
    const float tsv = tmp_s[b * 256 + t], gv = g[t], btv = bta[t];
#pragma unroll
    for (int j = 0; j < 4; j++) {
        float val = tokens[(tk0 + j) * 256 + t] + tsv;
        tr[j * 256 + t] = val;
        float s = val, q = val * val;
#pragma unroll
        for (int off = 32; off; off >>= 1) { s += __shfl_down(s, off); q += __shfl_down(q, off); }
        if (lane == 0) { red[j * 8 + w * 2] = s; red[j * 8 + w * 2 + 1] = q; }
    }
    __syncthreads();
#pragma unroll
    for (int j = 0; j < 4; j++) {
        float s = red[j * 8] + red[j * 8 + 2] + red[j * 8 + 4] + red[j * 8 + 6];
        float q = red[j * 8 + 1] + red[j * 8 + 3] + red[j * 8 + 5] + red[j * 8 + 7];
        float m = s * (1.f / 256.f);
        float var = q * (1.f / 256.f) - m * m;
        float r = rsqrtf(var + EPSF);
        tr[j * 256 + t] = (tr[j * 256 + t] - m) * r * gv + btv;
    }
    __syncthreads();
    float ak[4] = {0.f, 0.f, 0.f, 0.f}, av[4] = {0.f, 0.f, 0.f, 0.f};
    for (int i = 0; i < 256; i++) {
        float wk = Wk[i * 256 + t], wv = Wv[i * 256 + t];
#pragma unroll
        for (int j = 0; j < 4; j++) { ak[j] += tr[j * 256 + i] * wk; av[j] += tr[j * 256 + i] * wv; }
    }
    float bkv = bk[t], bvv = bv[t];
#pragma unroll
    for (int j = 0; j < 4; j++)
        kb16[((size_t)(b * 64 + tk0 + j)) * 256 + t] = f2bf(ak[j] + bkv);
    ushort4 vp;
    vp.x = f2bf(av[0] + bvv); vp.y = f2bf(av[1] + bvv);
    vp.z = f2bf(av[2] + bvv); vp.w = f2bf(av[3] + bvv);
    *(ushort4*)&vt16[((size_t)(b * 256 + t)) * 64 + tk0] = vp;
}

// ============================================================================
// Mega kernel v4 = R1 structure + packed (coalesced) weight fragments.
// Block = (b, 32-row s-tile). LDS = 35,328 B -> 4 blocks/CU.
// ============================================================================
__global__ __launch_bounds__(256, 4) void mega_kernel(
    const float* __restrict__ x, const float* __restrict__ stats,
    const float* __restrict__ pos,
    const __bf16* __restrict__ kb, const __bf16* __restrict__ vt,
    const float* __restrict__ gp,
    const float* __restrict__ lnq_g, const float* __restrict__ lnq_b,
    const float* __restrict__ lnf_g, const float* __restrict__ lnf_b,
    const __bf16* __restrict__ Wq_t, const float* __restrict__ bq,
    const __bf16* __restrict__ Wo_t, const float* __restrict__ bo,
    const __bf16* __restrict__ Wf1_t, const float* __restrict__ bf1,
    const __bf16* __restrict__ Wf2_t, const float* __restrict__ bf2,
    const float* __restrict__ gamma, float* __restrict__ out)
{
    __shared__ __align__(16) unsigned char smraw[35328];
    __bf16* Ab  = (__bf16*)smraw;                 // 32 x 264 bf16 = 16,896 B
    __bf16* PsB = (__bf16*)(smraw + 16896);       // 18,432 B scratch region
    __bf16* H   = (__bf16*)smraw;                 // overlay: 32 x 536 bf16 = 34,304 B
    float*  T   = (float*)smraw;                  // overlay: 32 x 268 f32  = 34,304 B
    float* psum   = (float*)(smraw + 16896);      // stats overlays (PsB region)
    float* psq    = psum + 256;
    float* rowred = psum + 512;

    const int blk  = blockIdx.x;        // 2048 = 16 b * 128 tiles
    const int b    = blk >> 7;
    const int s0   = (blk & 127) * 32;
    const int t    = threadIdx.x;
    const int w    = t >> 6;
    const int lane = t & 63;
    const int quad = lane >> 4;
    const int l16  = lane & 15;

    const float mg = stats[b * 4 + (t >> 6)];
    const float rg = stats[64 + b * 4 + (t >> 6)];
    const f32x4 z4 = {0.f, 0.f, 0.f, 0.f};

    // fragment base offset helper: tile16-index, #k-slices, k-slice
    // addr = ((tile*nks + ks)*4 + quad)*128 + l16*8   (1 KB contiguous / wave)
#define WFRAG(Wp, tile, nks, ks) \
    ld_bf8(&(Wp)[(((size_t)(tile) * (nks) + (ks)) * 4 + quad) * 128 + l16 * 8])

    // ---- S1: Ab = bf16(GN(x)+pos); row stats; LN_q in place ------------------
    {
        const float4* xp = (const float4*)(x + (size_t)(b * 256 + t) * 4096 + s0);
        float xv[32];
#pragma unroll
        for (int i = 0; i < 8; i++) {
            float4 v = xp[i];
            xv[4*i] = v.x; xv[4*i+1] = v.y; xv[4*i+2] = v.z; xv[4*i+3] = v.w;
        }
#pragma unroll
        for (int i = 0; i < 32; i++)
            Ab[i * 264 + t] = (__bf16)((xv[i] - mg) * rg + pos[(size_t)(s0 + i) * 256 + t]);
    }
    __syncthreads();
    {
        int sl = t & 31, cg = t >> 5;
        float s = 0.f, q = 0.f;
#pragma unroll
        for (int j = 0; j < 4; j++) {
            bf16x8 v8 = ld_bf8(&Ab[sl * 264 + cg * 32 + j * 8]);
#pragma unroll
            for (int e = 0; e < 8; e++) { float f = (float)v8[e]; s += f; q += f * f; }
        }
        psum[cg * 32 + sl] = s; psq[cg * 32 + sl] = q;
    }
    __syncthreads();
    if (t < 32) {
        float S = 0.f, Q = 0.f;
        for (int p = 0; p < 8; p++) { S += psum[p * 32 + t]; Q += psq[p * 32 + t]; }
        float m = S * (1.f / 256.f);
        float var = Q * (1.f / 256.f) - m * m;
        rowred[t * 2] = m; rowred[t * 2 + 1] = rsqrtf(var + EPSF);
    }
    __syncthreads();
    {
        float gq = lnq_g[t], bqv = lnq_b[t];
#pragma unroll
        for (int i = 0; i < 32; i++) {
            float v = (float)Ab[i * 264 + t];
            Ab[i * 264 + t] = (__bf16)((v - rowred[i * 2]) * rowred[i * 2 + 1] * gq + bqv);
        }
    }
    __syncthreads();

    // ---- S2: q = Ab @ Wq + bq -> Ab (wave: 32 rows x 64 cols) ----------------
    {
        bf16x8 af[2][8];
#pragma unroll
        for (int rt = 0; rt < 2; rt++)
#pragma unroll
            for (int ks = 0; ks < 8; ks++)
                af[rt][ks] = ld_bf8(&Ab[(rt * 16 + l16) * 264 + ks * 32 + quad * 8]);
        __syncthreads();   // all waves' A-frags loaded before Ab overwrite
#pragma unroll
        for (int nt = 0; nt < 4; nt++) {
            int n = w * 64 + nt * 16 + l16;
            f32x4 a0 = z4, a1 = z4;
#pragma unroll
            for (int ks = 0; ks < 8; ks++) {
                bf16x8 bv = WFRAG(Wq_t, w * 4 + nt, 8, ks);
                a0 = MFMA16(af[0][ks], bv, a0);
                a1 = MFMA16(af[1][ks], bv, a1);
            }
            float bias = bq[n];
#pragma unroll
            for (int r = 0; r < 4; r++) {
                Ab[(quad * 4 + r) * 264 + n]        = (__bf16)(a0[r] + bias);
                Ab[(16 + quad * 4 + r) * 264 + n]   = (__bf16)(a1[r] + bias);
            }
        }
    }
    // no barrier: S3 wave w reads exactly the cols wave w just wrote

    // ---- S3: attention, head = w, 32 rows ------------------------------------
    {
        const int h = w;
        __bf16* Psw = PsB + w * 32 * 72;
        bf16x8 qa[2][2];
#pragma unroll
        for (int rt = 0; rt < 2; rt++)
#pragma unroll
            for (int k0 = 0; k0 < 2; k0++)
                qa[rt][k0] = ld_bf8(&Ab[(rt * 16 + l16) * 264 + h * 64 + k0 * 32 + quad * 8]);
        f32x4 sa[2][4];
#pragma unroll
        for (int rt = 0; rt < 2; rt++)
#pragma unroll
            for (int nt = 0; nt < 4; nt++) sa[rt][nt] = z4;
#pragma unroll
        for (int nt = 0; nt < 4; nt++)
#pragma unroll
            for (int k0 = 0; k0 < 2; k0++) {
                bf16x8 kv8 = ld_bf8(&kb[((size_t)(b * 64 + nt * 16 + l16)) * 256 + h * 64 + k0 * 32 + quad * 8]);
                sa[0][nt] = MFMA16(qa[0][k0], kv8, sa[0][nt]);
                sa[1][nt] = MFMA16(qa[1][k0], kv8, sa[1][nt]);
            }
        // softmax per row; P -> Psw (bf16)
#pragma unroll
        for (int rt = 0; rt < 2; rt++)
#pragma unroll
            for (int r = 0; r < 4; r++) {
                float e0 = sa[rt][0][r] * 0.25f, e1 = sa[rt][1][r] * 0.25f;
                float e2 = sa[rt][2][r] * 0.25f, e3 = sa[rt][3][r] * 0.25f;
                float mx = fmaxf(fmaxf(e0, e1), fmaxf(e2, e3));
#pragma unroll
                for (int off = 1; off < 16; off <<= 1) mx = fmaxf(mx, __shfl_xor(mx, off));
                e0 = __expf(e0 - mx); e1 = __expf(e1 - mx);
                e2 = __expf(e2 - mx); e3 = __expf(e3 - mx);
                float sum = e0 + e1 + e2 + e3;
#pragma unroll
                for (int off = 1; off < 16; off <<= 1) sum += __shfl_xor(sum, off);
                float inv = 1.f / sum;
                int row = rt * 16 + quad * 4 + r;
                Psw[row * 72 +  0 + l16] = (__bf16)(e0 * inv);
                Psw[row * 72 + 16 + l16] = (__bf16)(e1 * inv);
                Psw[row * 72 + 32 + l16] = (__bf16)(e2 * inv);
                Psw[row * 72 + 48 + l16] = (__bf16)(e3 * inv);
            }
        // O = P @ V_h -> Ab cols [h*64, h*64+64)  (same-wave LDS, in order)
        bf16x8 pa[2][2];
#pragma unroll
        for (int rt = 0; rt < 2; rt++)
#pragma unroll
            for (int k0 = 0; k0 < 2; k0++)
                pa[rt][k0] = ld_bf8(&Psw[(rt * 16 + l16) * 72 + k0 * 32 + quad * 8]);
#pragma unroll
        for (int nt = 0; nt < 4; nt++) {
            f32x4 o0 = z4, o1 = z4;
#pragma unroll
            for (int k0 = 0; k0 < 2; k0++) {
                bf16x8 vv = ld_bf8(&vt[((size_t)(b * 256 + h * 64 + nt * 16 + l16)) * 64 + k0 * 32 + quad * 8]);
                o0 = MFMA16(pa[0][k0], vv, o0);
                o1 = MFMA16(pa[1][k0], vv, o1);
            }
#pragma unroll
            for (int r = 0; r < 4; r++) {
                Ab[(quad * 4 + r) * 264 + h * 64 + nt * 16 + l16]      = (__bf16)o0[r];
                Ab[(16 + quad * 4 + r) * 264 + h * 64 + nt * 16 + l16] = (__bf16)o1[r];
            }
        }
    }
    __syncthreads();

    // ---- S4: sc = Ab @ Wo + bo -> f32 registers (no LDS) ---------------------
    f32x4 scf[2][4];
    {
        bf16x8 af[2][8];
#pragma unroll
        for (int rt = 0; rt < 2; rt++)
#pragma unroll
            for (int ks = 0; ks < 8; ks++)
                af[rt][ks] = ld_bf8(&Ab[(rt * 16 + l16) * 264 + ks * 32 + quad * 8]);
#pragma unroll
        for (int nt = 0; nt < 4; nt++) {
            int n = w * 64 + nt * 16 + l16;
            f32x4 a0 = z4, a1 = z4;
#pragma unroll
            for (int ks = 0; ks < 8; ks++) {
                bf16x8 bv = WFRAG(Wo_t, w * 4 + nt, 8, ks);
                a0 = MFMA16(af[0][ks], bv, a0);
                a1 = MFMA16(af[1][ks], bv, a1);
            }
            float bias = bo[n];
#pragma unroll
            for (int r = 0; r < 4; r++) { a0[r] += bias; a1[r] += bias; }
            scf[0][nt] = a0;
            scf[1][nt] = a1;
        }
    }

    // ---- S5: row stats of sc from registers ----------------------------------
    {
#pragma unroll
        for (int rt = 0; rt < 2; rt++)
#pragma unroll
            for (int r = 0; r < 4; r++) {
                float s = scf[rt][0][r] + scf[rt][1][r] + scf[rt][2][r] + scf[rt][3][r];
                float q = scf[rt][0][r] * scf[rt][0][r] + scf[rt][1][r] * scf[rt][1][r]
                        + scf[rt][2][r] * scf[rt][2][r] + scf[rt][3][r] * scf[rt][3][r];
#pragma unroll
                for (int mk = 1; mk < 16; mk <<= 1) { s += __shfl_xor(s, mk); q += __shfl_xor(q, mk); }
                if (l16 == 0) {
                    int row = rt * 16 + quad * 4 + r;
                    psum[row * 4 + w] = s;
                    psq[row * 4 + w]  = q;
                }
            }
    }
    __syncthreads();
    if (t < 32) {
        float S = psum[t * 4] + psum[t * 4 + 1] + psum[t * 4 + 2] + psum[t * 4 + 3];
        float Q = psq[t * 4]  + psq[t * 4 + 1]  + psq[t * 4 + 2]  + psq[t * 4 + 3];
        float m = S * (1.f / 256.f);
        float var = Q * (1.f / 256.f) - m * m;
        rowred[t * 2] = m; rowred[t * 2 + 1] = rsqrtf(var + EPSF);
    }
    __syncthreads();

    // ---- LN_f from registers -> Ab (bf16, MFMA-A layout) ---------------------
    {
        float gf[4], bff[4];
#pragma unroll
        for (int nt = 0; nt < 4; nt++) {
            int n = w * 64 + nt * 16 + l16;
            gf[nt] = lnf_g[n]; bff[nt] = lnf_b[n];
        }
#pragma unroll
        for (int rt = 0; rt < 2; rt++)
#pragma unroll
            for (int r = 0; r < 4; r++) {
                int row = rt * 16 + quad * 4 + r;
                float m = rowred[row * 2], ri = rowred[row * 2 + 1];
#pragma unroll
                for (int nt = 0; nt < 4; nt++) {
                    int n = w * 64 + nt * 16 + l16;
                    Ab[row * 264 + n] = (__bf16)((scf[rt][nt][r] - m) * ri * gf[nt] + bff[nt]);
                }
            }
    }
    __syncthreads();

    // ---- FFN: FF1 full-width into H (overlay), one exchange barrier, FF2 -----
    f32x4 acc2[2][4];
#pragma unroll
    for (int rt = 0; rt < 2; rt++)
#pragma unroll
        for (int nt = 0; nt < 4; nt++) acc2[rt][nt] = z4;
    {
        bf16x8 fa[2][8];
#pragma unroll
        for (int rt = 0; rt < 2; rt++)
#pragma unroll
            for (int ks = 0; ks < 8; ks++)
                fa[rt][ks] = ld_bf8(&Ab[(rt * 16 + l16) * 264 + ks * 32 + quad * 8]);
        __syncthreads();   // all fa loaded; H overlay (covers Ab+PsB) now safe
        // FF1: wave w computes h1 cols [w*128, w*128+128) for all 32 rows
#pragma unroll
        for (int c = 0; c < 8; c++) {
            int n1 = w * 128 + c * 16 + l16;
            f32x4 h0 = z4, h1 = z4;
#pragma unroll
            for (int ks = 0; ks < 8; ks++) {
                bf16x8 bv = WFRAG(Wf1_t, w * 8 + c, 8, ks);
                h0 = MFMA16(fa[0][ks], bv, h0);
                h1 = MFMA16(fa[1][ks], bv, h1);
            }
            float b1v = bf1[n1];
#pragma unroll
            for (int r = 0; r < 4; r++) {
                float u0 = h0[r] + b1v;
                float u1 = h1[r] + b1v;
                H[(quad * 4 + r) * 536 + n1]      = (__bf16)(u0 / (1.f + __expf(-u0)));
                H[(16 + quad * 4 + r) * 536 + n1] = (__bf16)(u1 / (1.f + __expf(-u1)));
            }
        }
        __syncthreads();   // full H visible
        // FF2: accumulate over K=512
#pragma unroll
        for (int k0 = 0; k0 < 16; k0++) {
            bf16x8 ha0 = ld_bf8(&H[(size_t)l16 * 536 + k0 * 32 + quad * 8]);
            bf16x8 ha1 = ld_bf8(&H[(size_t)(16 + l16) * 536 + k0 * 32 + quad * 8]);
#pragma unroll
            for (int nt = 0; nt < 4; nt++) {
                bf16x8 bv = WFRAG(Wf2_t, w * 4 + nt, 16, k0);
                acc2[0][nt] = MFMA16(ha0, bv, acc2[0][nt]);
                acc2[1][nt] = MFMA16(ha1, bv, acc2[1][nt]);
            }
        }
    }
    __syncthreads();   // all H reads done before T overlay writes

    // ---- sc_final = sc + ffn + bf2 -> T (f32 transpose buffer) ---------------
    {
#pragma unroll
        for (int nt = 0; nt < 4; nt++) {
            int n = w * 64 + nt * 16 + l16;
            float b2 = bf2[n];
#pragma unroll
            for (int rt = 0; rt < 2; rt++)
#pragma unroll
                for (int r = 0; r < 4; r++)
                    T[(rt * 16 + quad * 4 + r) * 268 + n] = scf[rt][nt][r] + acc2[rt][nt][r] + b2;
        }
    }
    __syncthreads();

    // ---- S6: out[b,c,s] = GN(x)*scale + shift + sc*gamma ---------------------
    {
        const float scl = gp[b * 512 + t];
        const float sft = gp[b * 512 + 256 + t];
        const float gm  = gamma[t];
        const float4* xp = (const float4*)(x + (size_t)(b * 256 + t) * 4096 + s0);
        float4* op = (float4*)(out + (size_t)(b * 256 + t) * 4096 + s0);
#pragma unroll
        for (int ii = 0; ii < 8; ii++) {
            float4 xv = xp[ii];
            float4 o;
            o.x = (xv.x - mg) * rg * scl + sft + T[(ii * 4 + 0) * 268 + t] * gm;
            o.y = (xv.y - mg) * rg * scl + sft + T[(ii * 4 + 1) * 268 + t] * gm;
            o.z = (xv.z - mg) * rg * scl + sft + T[(ii * 4 + 2) * 268 + t] * gm;
            o.w = (xv.w - mg) * rg * scl + sft + T[(ii * 4 + 3) * 268 + t] * gm;
            op[ii] = o;
        }
    }
#undef WFRAG
}

// ============================================================================
extern "C" void kernel_launch(void* const* d_in, const int* in_sizes, int n_in,
                              void* d_out, int out_size, void* d_ws, size_t ws_size,
                              hipStream_t stream) {
    (void)in_sizes; (void)n_in; (void)out_size; (void)ws_size;
    const float* x      = (const float*)d_in[0];
    const float* style  = (const float*)d_in[1];
    const float* Wg     = (const float*)d_in[2];
    const float* bg     = (const float*)d_in[3];
    const float* tokens = (const float*)d_in[4];
    const float* Ws     = (const float*)d_in[5];
    const float* bs     = (const float*)d_in[6];
    const float* Wp1    = (const float*)d_in[7];
    const float* bp1    = (const float*)d_in[8];
    const float* Wp2    = (const float*)d_in[9];
    const float* bp2    = (const float*)d_in[10];
    const float* ln_t_g = (const float*)d_in[11];
    const float* ln_t_b = (const float*)d_in[12];
    const float* ln_q_g = (const float*)d_in[13];
    const float* ln_q_b = (const float*)d_in[14];
    const float* ln_f_g = (const float*)d_in[15];
    const float* ln_f_b = (const float*)d_in[16];
    const float* Wq     = (const float*)d_in[17];
    const float* bq     = (const float*)d_in[18];
    const float* Wk     = (const float*)d_in[19];
    const float* bk     = (const float*)d_in[20];
    const float* Wv     = (const float*)d_in[21];
    const float* bv     = (const float*)d_in[22];
    const float* Wo     = (const float*)d_in[23];
    const float* bo     = (const float*)d_in[24];
    const float* Wf1    = (const float*)d_in[25];
    const float* bf1    = (const float*)d_in[26];
    const float* Wf2    = (const float*)d_in[27];
    const float* bf2    = (const float*)d_in[28];
    const float* gamma  = (const float*)d_in[29];
    float* out = (float*)d_out;

    // d_ws layout (~7.1 MB)
    float* ws = (float*)d_ws;
    float* part  = ws;               // 2048
    float* stats = part  + 2048;     // 128
    float* gpb   = stats + 128;      // 8192
    float* tmp_s = gpb   + 8192;     // 4096
    float* tokb  = tmp_s + 4096;     // 262144 (unused, kept for layout stability)
    float* posb  = tokb  + 262144;   // 1048576
    unsigned short* kb16  = (unsigned short*)(posb + 1048576); // 262144 bf16
    unsigned short* vt16  = kb16  + 262144;                    // 262144
    unsigned short* wq_t  = vt16  + 262144;                    // 65536
    unsigned short* wo_t  = wq_t  + 65536;                     // 65536
    unsigned short* wf1_t = wo_t  + 65536;                     // 131072
    unsigned short* wf2_t = wf1_t + 131072;                    // 131072

    setup1_kernel<<<1712, 256, 0, stream>>>(x, part, style, Wg, bg, Ws, bs, gpb, tmp_s,
                                            Wp1, bp1, Wp2, bp2, posb,
                                            Wq, Wo, Wf1, Wf2,
                                            wq_t, wo_t, wf1_t, wf2_t);
    kv2_kernel<<<257, 256, 0, stream>>>(part, stats, tokens, tmp_s, ln_t_g, ln_t_b,
                                        Wk, bk, Wv, bv, kb16, vt16);
    mega_kernel<<<2048, 256, 0, stream>>>(x, stats, posb,
                                          (const __bf16*)kb16, (const __bf16*)vt16, gpb,
                                          ln_q_g, ln_q_b, ln_f_g, ln_f_b,
                                          (const __bf16*)wq_t, bq,
                                          (const __bf16*)wo_t, bo,
                                          (const __bf16*)wf1_t, bf1,
                                          (const __bf16*)wf2_t, bf2,
                                          gamma, out);
}

// Round 4
// 361.732 us; speedup vs baseline: 1.3548x; 1.1209x over previous
//
#include <hip/hip_runtime.h>
#include <hip/hip_bf16.h>

#define EPSF 1e-5f

typedef __bf16 bf16x8 __attribute__((ext_vector_type(8)));
typedef float  f32x4  __attribute__((ext_vector_type(4)));
#define MFMA16(a, b, c) __builtin_amdgcn_mfma_f32_16x16x32_bf16((a), (b), (c), 0, 0, 0)

__device__ __forceinline__ bf16x8 ld_bf8(const __bf16* p) { return *(const bf16x8*)p; }

__device__ __forceinline__ unsigned short f2bf(float x) {
    unsigned int u = __float_as_uint(x);
    unsigned int r = (u + 0x7fffu + ((u >> 16) & 1u)) >> 16;
    return (unsigned short)r;
}

// Packed fragment layout: [n>>4][k>>5][(k>>3)&3][n&15][k&7]
// -> one wave MFMA B-fragment (16 lanes l16 x 4 quads x 8 elems) = 512
//    CONTIGUOUS bytes per quad-group, 4 quads contiguous -> 512B*4=2KB? No:
//    per (tile,ks) the full wave fragment is 4*128B = 512B contiguous.
__device__ __forceinline__ size_t pk_idx(int n, int k, int K) {
    return ((size_t)(((n >> 4) * (K >> 5) + (k >> 5)) * 4 + ((k >> 3) & 3)) * 16
            + (n & 15)) * 8 + (k & 7);
}

// ============================================================================
// setup1: gn_partial | stylegp | 4x wtrans | pos | kvproj  (one kernel, 2 total)
// grid = 1024 + 32 + 64 + 64 + 128 + 128 + 256 + 256 = 1952
// ============================================================================
__device__ void wtrans_body(const float* __restrict__ W, unsigned short* __restrict__ Wt,
                            int K, int N, int L, int t, float* tile /*32x33*/) {
    int ktiles = K >> 5;
    int kt = L % ktiles, ntl = L / ktiles;
    int k0 = kt * 32, n0 = ntl * 32;
    int tc = t & 31, tr = t >> 5;
#pragma unroll
    for (int j = 0; j < 4; j++)
        tile[(tr + j * 8) * 33 + tc] = W[(size_t)(k0 + tr + j * 8) * N + n0 + tc];
    __syncthreads();
#pragma unroll
    for (int j = 0; j < 4; j++) {
        int r = tr + j * 8;
        Wt[pk_idx(n0 + r, k0 + tc, K)] = f2bf(tile[tc * 33 + r]);
    }
}

__global__ __launch_bounds__(256) void setup1_kernel(
    const float* __restrict__ x, float* __restrict__ part,
    const float* __restrict__ style, const float* __restrict__ Wg,
    const float* __restrict__ bg, const float* __restrict__ Ws,
    const float* __restrict__ bs, float* __restrict__ gp,
    const float* __restrict__ Wp1, const float* __restrict__ bp1,
    const float* __restrict__ Wp2, const float* __restrict__ bp2,
    float* __restrict__ pos,
    const float* __restrict__ Wq, const float* __restrict__ Wo,
    const float* __restrict__ Wf1, const float* __restrict__ Wf2,
    unsigned short* __restrict__ wq_t, unsigned short* __restrict__ wo_t,
    unsigned short* __restrict__ wf1_t, unsigned short* __restrict__ wf2_t,
    const float* __restrict__ tokens,
    const float* __restrict__ ltg, const float* __restrict__ ltb,
    const float* __restrict__ Wk, const float* __restrict__ bk,
    const float* __restrict__ Wv, const float* __restrict__ bv,
    unsigned short* __restrict__ kb16, unsigned short* __restrict__ vt16)
{
    __shared__ float sm[4096];   // 16 KB, carved per role
    const int L = blockIdx.x, t = threadIdx.x;

    if (L < 1024) {
        // ---- GroupNorm partial stats: (b,g) = L>>4, sub = L&15 --------------
        int bg_ = L >> 4, sub = L & 15;
        const float4* p = (const float4*)(x + bg_ * 262144 + sub * 16384);
        float s = 0.f, q = 0.f;
#pragma unroll
        for (int i = 0; i < 16; i++) {
            float4 v = p[i * 256 + t];
            s += v.x + v.y + v.z + v.w;
            q += v.x * v.x + v.y * v.y + v.z * v.z + v.w * v.w;
        }
#pragma unroll
        for (int off = 32; off; off >>= 1) { s += __shfl_down(s, off); q += __shfl_down(q, off); }
        int lane = t & 63, w = t >> 6;
        if (lane == 0) { sm[w * 2] = s; sm[w * 2 + 1] = q; }
        __syncthreads();
        if (t == 0) {
            part[L * 2]     = sm[0] + sm[2] + sm[4] + sm[6];
            part[L * 2 + 1] = sm[1] + sm[3] + sm[5] + sm[7];
        }
    } else if (L < 1056) {
        // ---- style proj (gp only: scale/shift halves) ------------------------
        int lb = L - 1024, b = lb >> 1, role = lb & 1;
        float* st = sm;
        st[t] = style[b * 512 + t];
        st[256 + t] = style[b * 512 + 256 + t];
        __syncthreads();
        int c = role * 256 + t;
        float acc = 0.f;
        for (int i = 0; i < 512; i++) acc += st[i] * Wg[i * 512 + c];
        gp[b * 512 + c] = acc + bg[c];
    } else if (L < 1120) {
        wtrans_body(Wq, wq_t, 256, 256, L - 1056, t, sm);
    } else if (L < 1184) {
        wtrans_body(Wo, wo_t, 256, 256, L - 1120, t, sm);
    } else if (L < 1312) {
        wtrans_body(Wf1, wf1_t, 256, 512, L - 1184, t, sm);
    } else if (L < 1440) {
        wtrans_body(Wf2, wf2_t, 512, 256, L - 1312, t, sm);
    } else if (L < 1696) {
        // ---- pos: 16 positions per block ------------------------------------
        int r = L - 1440, s0 = r * 16;
        float* pe = sm;    // 16 x 256
#pragma unroll
        for (int i = 0; i < 16; i++) {
            int sx = s0 + i;
            float gx = -1.f + 2.f * (float)(sx & 63) * (1.f / 63.f);
            float gy = -1.f + 2.f * (float)(sx >> 6) * (1.f / 63.f);
            float h = gx * Wp1[t] + gy * Wp1[256 + t] + bp1[t];
            pe[i * 256 + t] = h / (1.f + __expf(-h));
        }
        __syncthreads();
        float acc[16];
#pragma unroll
        for (int i = 0; i < 16; i++) acc[i] = 0.f;
#pragma unroll 4
        for (int k = 0; k < 256; k++) {
            float wv = Wp2[k * 256 + t];
#pragma unroll
            for (int i = 0; i < 16; i++) acc[i] += pe[i * 256 + k] * wv;
        }
        float bp = bp2[t];
#pragma unroll
        for (int i = 0; i < 16; i++) pos[(size_t)(s0 + i) * 256 + t] = acc[i] + bp;
    } else {
        // ---- kvproj: self-contained token-LN + K/V proj, packed stores -------
        int lb = L - 1696;
        int b = lb >> 4, tk0 = (lb & 15) * 4;
        float* st = sm;            // 512
        float* tr = sm + 512;      // 1024
        float* red = sm + 1536;    // 32
        st[t] = style[b * 512 + t];
        st[256 + t] = style[b * 512 + 256 + t];
        __syncthreads();
        float acc = 0.f;
        for (int i = 0; i < 512; i++) acc += st[i] * Ws[i * 256 + t];
        const float ts = acc + bs[t];
        const int lane = t & 63, wv_ = t >> 6;
        const float gv = ltg[t], btv = ltb[t];
#pragma unroll
        for (int j = 0; j < 4; j++) {
            float val = tokens[(tk0 + j) * 256 + t] + ts;
            tr[j * 256 + t] = val;
            float s = val, q = val * val;
#pragma unroll
            for (int off = 32; off; off >>= 1) { s += __shfl_down(s, off); q += __shfl_down(q, off); }
            if (lane == 0) { red[j * 8 + wv_ * 2] = s; red[j * 8 + wv_ * 2 + 1] = q; }
        }
        __syncthreads();
#pragma unroll
        for (int j = 0; j < 4; j++) {
            float s = red[j * 8] + red[j * 8 + 2] + red[j * 8 + 4] + red[j * 8 + 6];
            float q = red[j * 8 + 1] + red[j * 8 + 3] + red[j * 8 + 5] + red[j * 8 + 7];
            float m = s * (1.f / 256.f);
            float var = q * (1.f / 256.f) - m * m;
            float r = rsqrtf(var + EPSF);
            tr[j * 256 + t] = (tr[j * 256 + t] - m) * r * gv + btv;
        }
        __syncthreads();
        float ak[4] = {0.f, 0.f, 0.f, 0.f}, av[4] = {0.f, 0.f, 0.f, 0.f};
        for (int i = 0; i < 256; i++) {
            float wk = Wk[i * 256 + t], wvv = Wv[i * 256 + t];
#pragma unroll
            for (int j = 0; j < 4; j++) { ak[j] += tr[j * 256 + i] * wk; av[j] += tr[j * 256 + i] * wvv; }
        }
        float bkv = bk[t], bvv = bv[t];
        // K packed: frag(h, nt, k0) lane l16 = token, elems = k0*32+quad*8+e of head
        {
            int h = t >> 6, k0c = (t >> 5) & 1, qd = (t >> 3) & 3, e = t & 7;
#pragma unroll
            for (int j = 0; j < 4; j++) {
                int tok = tk0 + j;
                kb16[(size_t)b * 16384
                     + ((((h * 4 + (tok >> 4)) * 2 + k0c) * 4 + qd) * 16 + (tok & 15)) * 8 + e]
                    = f2bf(ak[j] + bkv);
            }
        }
        // V packed: frag(h, nt, k0) lane l16 = ch, elems = tokens
        {
            int h = t >> 6, ntv = (t >> 4) & 3, l16v = t & 15;
            int k0t = tk0 >> 5, qdt = (tk0 >> 3) & 3, et0 = tk0 & 7;
            ushort4 vp;
            vp.x = f2bf(av[0] + bvv); vp.y = f2bf(av[1] + bvv);
            vp.z = f2bf(av[2] + bvv); vp.w = f2bf(av[3] + bvv);
            *(ushort4*)&vt16[(size_t)b * 16384
                + ((((h * 4 + ntv) * 2 + k0t) * 4 + qdt) * 16 + l16v) * 8 + et0] = vp;
        }
    }
}

// ============================================================================
// Mega kernel v5. Block = (b, 32-row s-tile). LDS = 35,328 B -> 4 blocks/CU.
// GN stats derived in prologue from part. All weight/KV loads: uniform base +
// 32-bit int offset (packed fragments). scf folded into acc2 before FFN.
// ============================================================================
__global__ __launch_bounds__(256, 4) void mega_kernel(
    const float* __restrict__ x, const float* __restrict__ part,
    const float* __restrict__ pos,
    const __bf16* __restrict__ kb, const __bf16* __restrict__ vt,
    const float* __restrict__ gp,
    const float* __restrict__ lnq_g, const float* __restrict__ lnq_b,
    const float* __restrict__ lnf_g, const float* __restrict__ lnf_b,
    const __bf16* __restrict__ Wq_t, const float* __restrict__ bq,
    const __bf16* __restrict__ Wo_t, const float* __restrict__ bo,
    const __bf16* __restrict__ Wf1_t, const float* __restrict__ bf1,
    const __bf16* __restrict__ Wf2_t, const float* __restrict__ bf2,
    const float* __restrict__ gamma, float* __restrict__ out)
{
    __shared__ __align__(16) unsigned char smraw[35328];
    __bf16* Ab  = (__bf16*)smraw;                 // 32 x 264 bf16 = 16,896 B
    __bf16* PsB = (__bf16*)(smraw + 16896);       // 18,432 B scratch region
    __bf16* H   = (__bf16*)smraw;                 // overlay: 32 x 536 bf16 = 34,304 B
    float*  T   = (float*)smraw;                  // overlay: 32 x 268 f32  = 34,304 B
    float* psum   = (float*)(smraw + 16896);      // stats overlays (PsB region)
    float* psq    = psum + 256;
    float* rowred = psum + 512;

    const int blk  = blockIdx.x;        // 2048 = 16 b * 128 tiles
    const int b    = blk >> 7;
    const int s0   = (blk & 127) * 32;
    const int t    = threadIdx.x;
    const int w    = t >> 6;
    const int lane = t & 63;
    const int quad = lane >> 4;
    const int l16  = lane & 15;

    // int fragment offsets (SGPR base + 32-bit voffset addressing)
    const int woff   = quad * 128 + l16 * 8;
    const int qkbase = w * 16384 + woff;              // Wq_t / Wo_t: +(nt*8+ks)*512
    const int ffbase = w * 32768 + woff;              // Wf1_t: +(c*8+ks)*512 ; Wf2_t: +(nt*16+k0)*512
    const int kvbase = b * 16384 + w * 4096 + woff;   // kb / vt: +(nt*2+k0)*512

    const f32x4 z4 = {0.f, 0.f, 0.f, 0.f};

    // ---- prologue: GN stats from part (replaces gn_final kernel) -------------
    if (t < 64) {
        int g = t >> 4, sub = t & 15;
        float s = part[((b * 4 + g) * 16 + sub) * 2];
        float q = part[((b * 4 + g) * 16 + sub) * 2 + 1];
#pragma unroll
        for (int off = 8; off; off >>= 1) { s += __shfl_xor(s, off); q += __shfl_xor(q, off); }
        if (sub == 0) {
            float m   = s * (1.f / 262144.f);
            float var = q * (1.f / 262144.f) - m * m;
            psum[g]     = m;
            psum[4 + g] = rsqrtf(var + EPSF);
        }
    }
    __syncthreads();
    const float mg = psum[t >> 6];
    const float rg = psum[4 + (t >> 6)];

    // ---- S1: Ab = bf16(GN(x)+pos); row stats; LN_q in place ------------------
    {
        const float4* xp = (const float4*)(x + (size_t)(b * 256 + t) * 4096 + s0);
        float xv[32];
#pragma unroll
        for (int i = 0; i < 8; i++) {
            float4 v = xp[i];
            xv[4*i] = v.x; xv[4*i+1] = v.y; xv[4*i+2] = v.z; xv[4*i+3] = v.w;
        }
#pragma unroll
        for (int i = 0; i < 32; i++)
            Ab[i * 264 + t] = (__bf16)((xv[i] - mg) * rg + pos[(size_t)(s0 + i) * 256 + t]);
    }
    __syncthreads();
    {
        int sl = t & 31, cg = t >> 5;
        float s = 0.f, q = 0.f;
#pragma unroll
        for (int j = 0; j < 4; j++) {
            bf16x8 v8 = ld_bf8(&Ab[sl * 264 + cg * 32 + j * 8]);
#pragma unroll
            for (int e = 0; e < 8; e++) { float f = (float)v8[e]; s += f; q += f * f; }
        }
        psum[cg * 32 + sl] = s; psq[cg * 32 + sl] = q;
    }
    __syncthreads();
    if (t < 32) {
        float S = 0.f, Q = 0.f;
        for (int p = 0; p < 8; p++) { S += psum[p * 32 + t]; Q += psq[p * 32 + t]; }
        float m = S * (1.f / 256.f);
        float var = Q * (1.f / 256.f) - m * m;
        rowred[t * 2] = m; rowred[t * 2 + 1] = rsqrtf(var + EPSF);
    }
    __syncthreads();
    {
        float gq = lnq_g[t], bqv = lnq_b[t];
#pragma unroll
        for (int i = 0; i < 32; i++) {
            float v = (float)Ab[i * 264 + t];
            Ab[i * 264 + t] = (__bf16)((v - rowred[i * 2]) * rowred[i * 2 + 1] * gq + bqv);
        }
    }
    __syncthreads();

    // ---- S2: q = Ab @ Wq + bq -> Ab (wave: 32 rows x 64 cols) ----------------
    {
        bf16x8 af[2][8];
#pragma unroll
        for (int rt = 0; rt < 2; rt++)
#pragma unroll
            for (int ks = 0; ks < 8; ks++)
                af[rt][ks] = ld_bf8(&Ab[(rt * 16 + l16) * 264 + ks * 32 + quad * 8]);
        __syncthreads();   // all waves' A-frags loaded before Ab overwrite
#pragma unroll
        for (int nt = 0; nt < 4; nt++) {
            int n = w * 64 + nt * 16 + l16;
            f32x4 a0 = z4, a1 = z4;
#pragma unroll
            for (int ks = 0; ks < 8; ks++) {
                bf16x8 bv = ld_bf8(&Wq_t[qkbase + (nt * 8 + ks) * 512]);
                a0 = MFMA16(af[0][ks], bv, a0);
                a1 = MFMA16(af[1][ks], bv, a1);
            }
            float bias = bq[n];
#pragma unroll
            for (int r = 0; r < 4; r++) {
                Ab[(quad * 4 + r) * 264 + n]        = (__bf16)(a0[r] + bias);
                Ab[(16 + quad * 4 + r) * 264 + n]   = (__bf16)(a1[r] + bias);
            }
        }
    }
    // no barrier: S3 wave w reads exactly the cols wave w just wrote

    // ---- S3: attention, head = w, 32 rows ------------------------------------
    {
        const int h = w;
        __bf16* Psw = PsB + w * 32 * 72;
        bf16x8 qa[2][2];
#pragma unroll
        for (int rt = 0; rt < 2; rt++)
#pragma unroll
            for (int k0 = 0; k0 < 2; k0++)
                qa[rt][k0] = ld_bf8(&Ab[(rt * 16 + l16) * 264 + h * 64 + k0 * 32 + quad * 8]);
        f32x4 sa[2][4];
#pragma unroll
        for (int rt = 0; rt < 2; rt++)
#pragma unroll
            for (int nt = 0; nt < 4; nt++) sa[rt][nt] = z4;
#pragma unroll
        for (int nt = 0; nt < 4; nt++)
#pragma unroll
            for (int k0 = 0; k0 < 2; k0++) {
                bf16x8 kv8 = ld_bf8(&kb[kvbase + (nt * 2 + k0) * 512]);
                sa[0][nt] = MFMA16(qa[0][k0], kv8, sa[0][nt]);
                sa[1][nt] = MFMA16(qa[1][k0], kv8, sa[1][nt]);
            }
        // softmax per row; P -> Psw (bf16)
#pragma unroll
        for (int rt = 0; rt < 2; rt++)
#pragma unroll
            for (int r = 0; r < 4; r++) {
                float e0 = sa[rt][0][r] * 0.25f, e1 = sa[rt][1][r] * 0.25f;
                float e2 = sa[rt][2][r] * 0.25f, e3 = sa[rt][3][r] * 0.25f;
                float mx = fmaxf(fmaxf(e0, e1), fmaxf(e2, e3));
#pragma unroll
                for (int off = 1; off < 16; off <<= 1) mx = fmaxf(mx, __shfl_xor(mx, off));
                e0 = __expf(e0 - mx); e1 = __expf(e1 - mx);
                e2 = __expf(e2 - mx); e3 = __expf(e3 - mx);
                float sum = e0 + e1 + e2 + e3;
#pragma unroll
                for (int off = 1; off < 16; off <<= 1) sum += __shfl_xor(sum, off);
                float inv = 1.f / sum;
                int row = rt * 16 + quad * 4 + r;
                Psw[row * 72 +  0 + l16] = (__bf16)(e0 * inv);
                Psw[row * 72 + 16 + l16] = (__bf16)(e1 * inv);
                Psw[row * 72 + 32 + l16] = (__bf16)(e2 * inv);
                Psw[row * 72 + 48 + l16] = (__bf16)(e3 * inv);
            }
        // O = P @ V_h -> Ab cols [h*64, h*64+64)  (same-wave LDS, in order)
        bf16x8 pa[2][2];
#pragma unroll
        for (int rt = 0; rt < 2; rt++)
#pragma unroll
            for (int k0 = 0; k0 < 2; k0++)
                pa[rt][k0] = ld_bf8(&Psw[(rt * 16 + l16) * 72 + k0 * 32 + quad * 8]);
#pragma unroll
        for (int nt = 0; nt < 4; nt++) {
            f32x4 o0 = z4, o1 = z4;
#pragma unroll
            for (int k0 = 0; k0 < 2; k0++) {
                bf16x8 vv = ld_bf8(&vt[kvbase + (nt * 2 + k0) * 512]);
                o0 = MFMA16(pa[0][k0], vv, o0);
                o1 = MFMA16(pa[1][k0], vv, o1);
            }
#pragma unroll
            for (int r = 0; r < 4; r++) {
                Ab[(quad * 4 + r) * 264 + h * 64 + nt * 16 + l16]      = (__bf16)o0[r];
                Ab[(16 + quad * 4 + r) * 264 + h * 64 + nt * 16 + l16] = (__bf16)o1[r];
            }
        }
    }
    __syncthreads();

    // ---- S4: sc = Ab @ Wo + bo -> f32 registers (no LDS) ---------------------
    f32x4 scf[2][4];
    {
        bf16x8 af[2][8];
#pragma unroll
        for (int rt = 0; rt < 2; rt++)
#pragma unroll
            for (int ks = 0; ks < 8; ks++)
                af[rt][ks] = ld_bf8(&Ab[(rt * 16 + l16) * 264 + ks * 32 + quad * 8]);
#pragma unroll
        for (int nt = 0; nt < 4; nt++) {
            int n = w * 64 + nt * 16 + l16;
            f32x4 a0 = z4, a1 = z4;
#pragma unroll
            for (int ks = 0; ks < 8; ks++) {
                bf16x8 bv = ld_bf8(&Wo_t[qkbase + (nt * 8 + ks) * 512]);
                a0 = MFMA16(af[0][ks], bv, a0);
                a1 = MFMA16(af[1][ks], bv, a1);
            }
            float bias = bo[n];
#pragma unroll
            for (int r = 0; r < 4; r++) { a0[r] += bias; a1[r] += bias; }
            scf[0][nt] = a0;
            scf[1][nt] = a1;
        }
    }

    // ---- S5: row stats of sc from registers ----------------------------------
    {
#pragma unroll
        for (int rt = 0; rt < 2; rt++)
#pragma unroll
            for (int r = 0; r < 4; r++) {
                float s = scf[rt][0][r] + scf[rt][1][r] + scf[rt][2][r] + scf[rt][3][r];
                float q = scf[rt][0][r] * scf[rt][0][r] + scf[rt][1][r] * scf[rt][1][r]
                        + scf[rt][2][r] * scf[rt][2][r] + scf[rt][3][r] * scf[rt][3][r];
#pragma unroll
                for (int mk = 1; mk < 16; mk <<= 1) { s += __shfl_xor(s, mk); q += __shfl_xor(q, mk); }
                if (l16 == 0) {
                    int row = rt * 16 + quad * 4 + r;
                    psum[row * 4 + w] = s;
                    psq[row * 4 + w]  = q;
                }
            }
    }
    __syncthreads();
    if (t < 32) {
        float S = psum[t * 4] + psum[t * 4 + 1] + psum[t * 4 + 2] + psum[t * 4 + 3];
        float Q = psq[t * 4]  + psq[t * 4 + 1]  + psq[t * 4 + 2]  + psq[t * 4 + 3];
        float m = S * (1.f / 256.f);
        float var = Q * (1.f / 256.f) - m * m;
        rowred[t * 2] = m; rowred[t * 2 + 1] = rsqrtf(var + EPSF);
    }
    __syncthreads();

    // ---- LN_f from registers -> Ab; then fold scf+bf2 into acc2 (kills scf) --
    f32x4 acc2[2][4];
    {
        float gf[4], bff[4];
#pragma unroll
        for (int nt = 0; nt < 4; nt++) {
            int n = w * 64 + nt * 16 + l16;
            gf[nt] = lnf_g[n]; bff[nt] = lnf_b[n];
        }
#pragma unroll
        for (int rt = 0; rt < 2; rt++)
#pragma unroll
            for (int r = 0; r < 4; r++) {
                int row = rt * 16 + quad * 4 + r;
                float m = rowred[row * 2], ri = rowred[row * 2 + 1];
#pragma unroll
                for (int nt = 0; nt < 4; nt++) {
                    int n = w * 64 + nt * 16 + l16;
                    Ab[row * 264 + n] = (__bf16)((scf[rt][nt][r] - m) * ri * gf[nt] + bff[nt]);
                }
            }
        // acc2 = scf + bf2  (FF2 accumulates on top; scf's live range ends here)
#pragma unroll
        for (int nt = 0; nt < 4; nt++) {
            float b2 = bf2[w * 64 + nt * 16 + l16];
#pragma unroll
            for (int rt = 0; rt < 2; rt++) {
                acc2[rt][nt] = scf[rt][nt];
#pragma unroll
                for (int r = 0; r < 4; r++) acc2[rt][nt][r] += b2;
            }
        }
    }
    __syncthreads();

    // ---- FFN: FF1 full-width into H (overlay), one exchange barrier, FF2 -----
    {
        bf16x8 fa[2][8];
#pragma unroll
        for (int rt = 0; rt < 2; rt++)
#pragma unroll
            for (int ks = 0; ks < 8; ks++)
                fa[rt][ks] = ld_bf8(&Ab[(rt * 16 + l16) * 264 + ks * 32 + quad * 8]);
        __syncthreads();   // all fa loaded; H overlay (covers Ab+PsB) now safe
        // FF1: wave w computes h1 cols [w*128, w*128+128) for all 32 rows
#pragma unroll
        for (int c = 0; c < 8; c++) {
            int n1 = w * 128 + c * 16 + l16;
            f32x4 h0 = z4, h1 = z4;
#pragma unroll
            for (int ks = 0; ks < 8; ks++) {
                bf16x8 bv = ld_bf8(&Wf1_t[ffbase + (c * 8 + ks) * 512]);
                h0 = MFMA16(fa[0][ks], bv, h0);
                h1 = MFMA16(fa[1][ks], bv, h1);
            }
            float b1v = bf1[n1];
#pragma unroll
            for (int r = 0; r < 4; r++) {
                float u0 = h0[r] + b1v;
                float u1 = h1[r] + b1v;
                H[(quad * 4 + r) * 536 + n1]      = (__bf16)(u0 / (1.f + __expf(-u0)));
                H[(16 + quad * 4 + r) * 536 + n1] = (__bf16)(u1 / (1.f + __expf(-u1)));
            }
        }
        __syncthreads();   // full H visible
        // FF2: accumulate over K=512
#pragma unroll
        for (int k0 = 0; k0 < 16; k0++) {
            bf16x8 ha0 = ld_bf8(&H[(size_t)l16 * 536 + k0 * 32 + quad * 8]);
            bf16x8 ha1 = ld_bf8(&H[(size_t)(16 + l16) * 536 + k0 * 32 + quad * 8]);
#pragma unroll
            for (int nt = 0; nt < 4; nt++) {
                bf16x8 bv = ld_bf8(&Wf2_t[ffbase + (nt * 16 + k0) * 512]);
                acc2[0][nt] = MFMA16(ha0, bv, acc2[0][nt]);
                acc2[1][nt] = MFMA16(ha1, bv, acc2[1][nt]);
            }
        }
    }
    __syncthreads();   // all H reads done before T overlay writes

    // ---- sc_final (= acc2, already includes sc + bf2) -> T (f32 transpose) ---
    {
#pragma unroll
        for (int nt = 0; nt < 4; nt++) {
            int n = w * 64 + nt * 16 + l16;
#pragma unroll
            for (int rt = 0; rt < 2; rt++)
#pragma unroll
                for (int r = 0; r < 4; r++)
                    T[(rt * 16 + quad * 4 + r) * 268 + n] = acc2[rt][nt][r];
        }
    }
    __syncthreads();

    // ---- S6: out[b,c,s] = GN(x)*scale + shift + sc*gamma ---------------------
    {
        const float scl = gp[b * 512 + t];
        const float sft = gp[b * 512 + 256 + t];
        const float gm  = gamma[t];
        const float4* xp = (const float4*)(x + (size_t)(b * 256 + t) * 4096 + s0);
        float4* op = (float4*)(out + (size_t)(b * 256 + t) * 4096 + s0);
#pragma unroll
        for (int ii = 0; ii < 8; ii++) {
            float4 xv = xp[ii];
            float4 o;
            o.x = (xv.x - mg) * rg * scl + sft + T[(ii * 4 + 0) * 268 + t] * gm;
            o.y = (xv.y - mg) * rg * scl + sft + T[(ii * 4 + 1) * 268 + t] * gm;
            o.z = (xv.z - mg) * rg * scl + sft + T[(ii * 4 + 2) * 268 + t] * gm;
            o.w = (xv.w - mg) * rg * scl + sft + T[(ii * 4 + 3) * 268 + t] * gm;
            op[ii] = o;
        }
    }
}

// ============================================================================
extern "C" void kernel_launch(void* const* d_in, const int* in_sizes, int n_in,
                              void* d_out, int out_size, void* d_ws, size_t ws_size,
                              hipStream_t stream) {
    (void)in_sizes; (void)n_in; (void)out_size; (void)ws_size;
    const float* x      = (const float*)d_in[0];
    const float* style  = (const float*)d_in[1];
    const float* Wg     = (const float*)d_in[2];
    const float* bg     = (const float*)d_in[3];
    const float* tokens = (const float*)d_in[4];
    const float* Ws     = (const float*)d_in[5];
    const float* bs     = (const float*)d_in[6];
    const float* Wp1    = (const float*)d_in[7];
    const float* bp1    = (const float*)d_in[8];
    const float* Wp2    = (const float*)d_in[9];
    const float* bp2    = (const float*)d_in[10];
    const float* ln_t_g = (const float*)d_in[11];
    const float* ln_t_b = (const float*)d_in[12];
    const float* ln_q_g = (const float*)d_in[13];
    const float* ln_q_b = (const float*)d_in[14];
    const float* ln_f_g = (const float*)d_in[15];
    const float* ln_f_b = (const float*)d_in[16];
    const float* Wq     = (const float*)d_in[17];
    const float* bq     = (const float*)d_in[18];
    const float* Wk     = (const float*)d_in[19];
    const float* bk     = (const float*)d_in[20];
    const float* Wv     = (const float*)d_in[21];
    const float* bv     = (const float*)d_in[22];
    const float* Wo     = (const float*)d_in[23];
    const float* bo     = (const float*)d_in[24];
    const float* Wf1    = (const float*)d_in[25];
    const float* bf1    = (const float*)d_in[26];
    const float* Wf2    = (const float*)d_in[27];
    const float* bf2    = (const float*)d_in[28];
    const float* gamma  = (const float*)d_in[29];
    float* out = (float*)d_out;

    // d_ws layout (~7.1 MB)
    float* ws = (float*)d_ws;
    float* part  = ws;               // 2048
    float* stats = part  + 2048;     // 128  (unused, kept for layout stability)
    float* gpb   = stats + 128;      // 8192
    float* tmp_s = gpb   + 8192;     // 4096 (unused)
    float* tokb  = tmp_s + 4096;     // 262144 (unused)
    float* posb  = tokb  + 262144;   // 1048576
    unsigned short* kb16  = (unsigned short*)(posb + 1048576); // 262144 bf16
    unsigned short* vt16  = kb16  + 262144;                    // 262144
    unsigned short* wq_t  = vt16  + 262144;                    // 65536
    unsigned short* wo_t  = wq_t  + 65536;                     // 65536
    unsigned short* wf1_t = wo_t  + 65536;                     // 131072
    unsigned short* wf2_t = wf1_t + 131072;                    // 131072

    setup1_kernel<<<1952, 256, 0, stream>>>(x, part, style, Wg, bg, Ws, bs, gpb,
                                            Wp1, bp1, Wp2, bp2, posb,
                                            Wq, Wo, Wf1, Wf2,
                                            wq_t, wo_t, wf1_t, wf2_t,
                                            tokens, ln_t_g, ln_t_b,
                                            Wk, bk, Wv, bv, kb16, vt16);
    mega_kernel<<<2048, 256, 0, stream>>>(x, part, posb,
                                          (const __bf16*)kb16, (const __bf16*)vt16, gpb,
                                          ln_q_g, ln_q_b, ln_f_g, ln_f_b,
                                          (const __bf16*)wq_t, bq,
                                          (const __bf16*)wo_t, bo,
                                          (const __bf16*)wf1_t, bf1,
                                          (const __bf16*)wf2_t, bf2,
                                          gamma, out);
}